// Round 7
// baseline (102.165 us; speedup 1.0000x reference)
//
#include <hip/hip_runtime.h>
#include <math.h>

// Problem constants (from reference setup_inputs)
namespace {
constexpr int B = 128;
constexpr int T = 2048;
constexpr int D = 128;
constexpr int Q = D / 4;             // 32 float4 per (b,t) row
constexpr int P = 64;
constexpr int TOUT = T + P;          // 2112
constexpr int NC = 32;               // chunks along T (best measured: R2/R5)
constexpr int L = T / NC;            // 64 per chunk
constexpr int CPB = 4;               // chunks per 128-thread block (float4 kernels)
constexpr float ALPHA = 0.94f;
constexpr float OMA = (float)(1.0 - 0.94);   // 1-alpha
constexpr float UCLIP = 1e-6f;
constexpr float SQRT2 = 1.41421356237309515f;
constexpr float INV_SQRT2 = 0.70710678118654752f;
constexpr float RMAX = 0.999998f;    // 1 - 2*UCLIP
}

// True vector type for __builtin_nontemporal_* (HIP float4 is a struct and
// is rejected by the builtin).
typedef float fx4 __attribute__((ext_vector_type(4)));

// ---------------------------------------------------------------------------
// Fast erfinv (M. Giles). Central branch covers |x|<~0.9966; tail branch is
// rare for ~normal data (skipped via execz when no lane takes it).
// ---------------------------------------------------------------------------
__device__ __forceinline__ float fast_erfinv(float x) {
    float w = -__logf(fmaf(-x, x, 1.0f));     // -log(1-x^2)
    float p;
    if (w < 5.0f) {
        w -= 2.5f;
        p = 2.81022636e-08f;
        p = fmaf(p, w, 3.43273939e-07f);
        p = fmaf(p, w, -3.5233877e-06f);
        p = fmaf(p, w, -4.39150654e-06f);
        p = fmaf(p, w, 0.00021858087f);
        p = fmaf(p, w, -0.00125372503f);
        p = fmaf(p, w, -0.00417768164f);
        p = fmaf(p, w, 0.246640727f);
        p = fmaf(p, w, 1.50140941f);
    } else {
        w = sqrtf(w) - 3.0f;
        p = -0.000200214257f;
        p = fmaf(p, w, 0.000100950558f);
        p = fmaf(p, w, 0.00134934322f);
        p = fmaf(p, w, -0.00367342844f);
        p = fmaf(p, w, 0.00573950773f);
        p = fmaf(p, w, -0.0076224613f);
        p = fmaf(p, w, 0.00943887047f);
        p = fmaf(p, w, 1.00167406f);
        p = fmaf(p, w, 2.83297682f);
    }
    return p * x;
}

// y = x - mu, v = scale^2 (clamped). r = 2F(t)-1 with t = y/sqrt(v), df=4:
//   r = y*(6v+y^2) * rsqrt((4v+y^2)^3)      (v^{3/2} cancels; no divide)
// then z = sqrt(2)*erfinv(clip(r)).
__device__ __forceinline__ float t_to_z(float y, float v) {
    float y2 = y * y;
    float a6 = fmaf(v, 6.0f, y2);
    float a4 = fmaf(v, 4.0f, y2);
    float m  = rsqrtf(a4);
    float m3 = m * m * m;
    float r  = y * a6 * m3;                        // in [-1, 1]
    r = fminf(fmaxf(r, -RMAX), RMAX);              // == clip(u,1e-6,1-1e-6)
    return SQRT2 * fast_erfinv(r);
}

// ---------------------------------------------------------------------------
// Kernel A (fx4): per (b, chunk-group of 4). Thread map: q=t&31 (d-quad),
// j=t>>5 (chunk in group). Partial sum + chunk-local EWMA tails of x, x^2.
// Default VGPR budget (no min-waves cap — R4's (128,8) caused spills).
// ---------------------------------------------------------------------------
__global__ __launch_bounds__(128) void kA(const fx4* __restrict__ x4,
                                          fx4* __restrict__ Spart,
                                          fx4* __restrict__ l1e,
                                          fx4* __restrict__ l2e) {
    const int t = threadIdx.x;
    const int q = t & (Q - 1);
    const int j = t >> 5;
    const int c = blockIdx.x * CPB + j;
    const int b = blockIdx.y;

    const fx4* xp = x4 + ((size_t)b * T + (size_t)c * L) * Q + q;

    float sm[4], l1[4], l2[4];
    {
        fx4 v = xp[0];
        #pragma unroll
        for (int i = 0; i < 4; ++i) {
            float xi = v[i];
            sm[i] = xi;
            float g2 = xi * xi;
            if (c == 0) { l1[i] = xi;       l2[i] = g2; }
            else        { l1[i] = OMA * xi; l2[i] = OMA * g2; }
        }
    }
    for (int k = 1; k < L; ++k) {
        fx4 v = xp[(size_t)k * Q];
        #pragma unroll
        for (int i = 0; i < 4; ++i) {
            float xi = v[i];
            sm[i] += xi;
            l1[i] = fmaf(ALPHA, l1[i], OMA * xi);
            l2[i] = fmaf(ALPHA, l2[i], OMA * (xi * xi));
        }
    }
    const size_t o = ((size_t)b * NC + c) * Q + q;
    Spart[o] = (fx4){sm[0], sm[1], sm[2], sm[3]};
    l1e[o]   = (fx4){l1[0], l1[1], l1[2], l1[3]};
    l2e[o]   = (fx4){l2[0], l2[1], l2[2], l2[3]};
}

// ---------------------------------------------------------------------------
// Kernel B: per (b,d) — stitch chunk carries exactly (scalar; same memory
// layout as the fx4 buffers). Pass 2 rewrites crw = carry2 - 2*mu*carry1
// into carry1. carry1 aliases Spart, carry2 aliases l1e (same-thread
// load-before-store) — NO __restrict__.
// ---------------------------------------------------------------------------
__global__ __launch_bounds__(256) void kB(const float* Spart,
                                          const float* l1e,
                                          const float* l2e,
                                          float* carry1,
                                          float* carry2,
                                          float* __restrict__ loc,
                                          float* __restrict__ scf) {
    const int tid = blockIdx.x * blockDim.x + threadIdx.x;   // b*D + d
    if (tid >= B * D) return;
    const int b = tid / D;
    const int d = tid % D;

    const float alphaL = (float)pow((double)ALPHA, (double)L);  // folded

    float sum = 0.0f, e1 = 0.0f, e2 = 0.0f;
    for (int c = 0; c < NC; ++c) {
        const size_t o = ((size_t)b * NC + c) * D + d;
        float sp = Spart[o];
        float t1 = l1e[o];
        float t2 = l2e[o];
        carry1[o] = e1;
        carry2[o] = e2;
        sum += sp;
        e1 = t1 + alphaL * e1;
        e2 = t2 + alphaL * e2;
    }

    const float mu = sum * (1.0f / (float)T);
    loc[tid] = mu;
    float ew = fmaxf(fmaf(mu, mu, fmaf(-2.0f * mu, e1, e2)), 0.0f);
    scf[tid] = fmaxf(sqrtf(0.5f * ew), 1e-5f);

    // fold carries: crw = carry2 - 2*mu*carry1 (stored into carry1)
    for (int c = 0; c < NC; ++c) {
        const size_t o = ((size_t)b * NC + c) * D + d;
        float c1 = carry1[o];
        float c2 = carry2[o];
        carry1[o] = fmaf(-2.0f * mu, c1, c2);
    }
}

// ---------------------------------------------------------------------------
// Kernel C (fx4): single fused EWMA scan, carry folded into initial state:
//   s_k = alpha*s_{k-1} + (1-alpha)*x*(x-2mu),  s_0 = base_0 + alpha*crw
//   v = max(0.5*s + 0.5*mu^2, 1e-10)
// 4 independent chains per thread (ILP for the serial t_to_z chain).
// NT stores keep x LLC-resident (R5's win).
// ---------------------------------------------------------------------------
__global__ __launch_bounds__(128) void kC(const fx4* __restrict__ x4,
                                          const fx4* __restrict__ crwb,
                                          const fx4* __restrict__ locg,
                                          fx4* __restrict__ out4) {
    const int t = threadIdx.x;
    const int q = t & (Q - 1);
    const int j = t >> 5;
    const int c = blockIdx.x * CPB + j;
    const int b = blockIdx.y;

    const size_t co = ((size_t)b * NC + c) * Q + q;
    const fx4 cv = crwb[co];
    const fx4 mv = locg[(size_t)b * Q + q];
    float crw[4], mu[4], twomu[4], mu2h[4];
    #pragma unroll
    for (int i = 0; i < 4; ++i) {
        crw[i]   = cv[i];
        mu[i]    = mv[i];
        twomu[i] = 2.0f * mu[i];
        mu2h[i]  = 0.5f * mu[i] * mu[i];
    }

    const fx4* xp = x4   + ((size_t)b * T    + (size_t)c * L) * Q + q;
    fx4*       op = out4 + ((size_t)b * TOUT + (size_t)c * L) * Q + q;

    float s[4];
    {
        fx4 v = xp[0];
        fx4 r_;
        #pragma unroll
        for (int i = 0; i < 4; ++i) {
            float xi = v[i];
            float g = xi * (xi - twomu[i]);
            float base = (c == 0) ? g : OMA * g;
            s[i] = fmaf(ALPHA, crw[i], base);
            float vv = fmaxf(fmaf(0.5f, s[i], mu2h[i]), 1e-10f);
            r_[i] = t_to_z(xi - mu[i], vv);
        }
        __builtin_nontemporal_store(r_, &op[0]);
    }
    for (int k = 1; k < L; ++k) {
        fx4 v = xp[(size_t)k * Q];
        fx4 r_;
        #pragma unroll
        for (int i = 0; i < 4; ++i) {
            float xi = v[i];
            float g = xi * (xi - twomu[i]);
            s[i] = fmaf(ALPHA, s[i], OMA * g);
            float vv = fmaxf(fmaf(0.5f, s[i], mu2h[i]), 1e-10f);
            r_[i] = t_to_z(xi - mu[i], vv);
        }
        __builtin_nontemporal_store(r_, &op[(size_t)k * Q]);
    }
}

// ---------------------------------------------------------------------------
// Kernel D: forecasts — u = clip(ndtr(z)), student-t(4) ppf closed form.
// ---------------------------------------------------------------------------
__global__ __launch_bounds__(256) void kD(const float* __restrict__ zf,
                                          const float* __restrict__ loc,
                                          const float* __restrict__ scf,
                                          float* __restrict__ out) {
    const int idx = blockIdx.x * blockDim.x + threadIdx.x;
    if (idx >= B * P * D) return;
    const int d  = idx % D;
    const int bp = idx / D;
    const int p  = bp % P;
    const int b  = bp / P;

    float zv = zf[idx];
    float u = 0.5f * erfcf(-zv * INV_SQRT2);            // ndtr
    u = fminf(fmaxf(u, UCLIP), 1.0f - UCLIP);

    float a = 4.0f * u * (1.0f - u);
    a = fminf(fmaxf(a, UCLIP), 1.0f);
    float sa = sqrtf(a);
    float inner = cosf(acosf(sa) * (1.0f / 3.0f)) / sa - 1.0f;
    float qv = 2.0f * sqrtf(fmaxf(inner, 0.0f));

    float sgn = (u > 0.5f) ? 1.0f : ((u < 0.5f) ? -1.0f : 0.0f);
    float val = sgn * qv * scf[b * D + d] + loc[b * D + d];

    __builtin_nontemporal_store(val, &out[((size_t)b * TOUT + T + p) * D + d]);
}

// ---------------------------------------------------------------------------
extern "C" void kernel_launch(void* const* d_in, const int* in_sizes, int n_in,
                              void* d_out, int out_size, void* d_ws, size_t ws_size,
                              hipStream_t stream) {
    const float* x  = (const float*)d_in[0];   // (B,T,D)
    const float* zf = (const float*)d_in[1];   // (B,P,D)
    float* out = (float*)d_out;                // (B,T+P,D)

    float* ws = (float*)d_ws;
    const size_t NCH = (size_t)B * NC * D;     // 524288
    float* Spart  = ws;                        // reused as carry1 / crw
    float* l1e    = Spart + NCH;               // reused as carry2
    float* l2e    = l1e + NCH;
    float* loc    = l2e + NCH;                 // B*D
    float* scf    = loc + (size_t)B * D;       // B*D
    float* carry1 = Spart;                     // alias (see kB)
    float* carry2 = l1e;                       // alias (see kB)

    kA<<<dim3(NC / CPB, B), 128, 0, stream>>>((const fx4*)x, (fx4*)Spart,
                                              (fx4*)l1e, (fx4*)l2e);
    kB<<<(B * D + 255) / 256, 256, 0, stream>>>(Spart, l1e, l2e, carry1, carry2, loc, scf);
    kC<<<dim3(NC / CPB, B), 128, 0, stream>>>((const fx4*)x, (const fx4*)carry1,
                                              (const fx4*)loc, (fx4*)out);
    kD<<<(B * P * D + 255) / 256, 256, 0, stream>>>(zf, loc, scf, out);
}

// Round 8
// 84.599 us; speedup vs baseline: 1.2076x; 1.2076x over previous
//
#include <hip/hip_runtime.h>
#include <math.h>

// Problem constants (from reference setup_inputs)
namespace {
constexpr int B = 128;
constexpr int T = 2048;
constexpr int D = 128;
constexpr int P = 64;
constexpr int TOUT = T + P;          // 2112
constexpr int NC = 32;               // chunks along T (best measured: R2/R5)
constexpr int L = T / NC;            // 64 per chunk
constexpr float ALPHA = 0.94f;
constexpr float OMA = (float)(1.0 - 0.94);   // 1-alpha
constexpr float UCLIP = 1e-6f;
constexpr float INV_SQRT2 = 0.70710678118654752f;
constexpr float RMAX = 0.999998f;    // 1 - 2*UCLIP
}

// ---------------------------------------------------------------------------
// z = sqrt(2)*erfinv(r), central branch ONLY, with sqrt(2) folded into the
// coefficients. Justification for dropping the tail branch: the EWMA gives
// ewma >= (1-alpha)*(x-mu)^2, hence t^2 <= 2/(1-alpha)... = 33.3 and
// |r| <= 0.9957 -> w = -log(1-r^2) <= 4.8 < 5 (the tail threshold). Even in
// the eps-clamp case (v=1e-10), |y|<=5.8e-5 forces |t|<=5.8. Float-rounding
// slop can push w marginally past 5; central-poly extrapolation error there
// is ~0.01-0.1, far below the 0.765 absmax threshold.
// ---------------------------------------------------------------------------
__device__ __forceinline__ float sqrt2_erfinv_central(float r) {
    float w = -__logf(fmaf(-r, r, 1.0f)) - 2.5f;   // -log(1-r^2) - 2.5
    float p;
    p = 3.9742594e-08f;                // = sqrt(2) * Giles central coeffs
    p = fmaf(p, w, 4.8546271e-07f);
    p = fmaf(p, w, -4.9828245e-06f);
    p = fmaf(p, w, -6.2105310e-06f);
    p = fmaf(p, w, 3.0912008e-04f);
    p = fmaf(p, w, -1.7730359e-03f);
    p = fmaf(p, w, -5.9081356e-03f);
    p = fmaf(p, w, 3.4880270e-01f);
    p = fmaf(p, w, 2.1233138e+00f);
    return p * r;
}

// y = x - mu, v = scale^2 (clamped). r = 2F(t)-1 with t = y/sqrt(v), df=4:
//   r = y*(6v+y^2) * rsqrt((4v+y^2)^3)      (v^{3/2} cancels; no divide)
// then z = sqrt(2)*erfinv(clip(r)).
__device__ __forceinline__ float t_to_z(float y, float v) {
    float y2 = y * y;
    float a6 = fmaf(v, 6.0f, y2);
    float a4 = fmaf(v, 4.0f, y2);
    float m  = rsqrtf(a4);
    float m3 = m * m * m;
    float r  = y * a6 * m3;                        // in [-1, 1]
    r = fminf(fmaxf(r, -RMAX), RMAX);              // == clip(u,1e-6,1-1e-6)
    return sqrt2_erfinv_central(r);
}

// ---------------------------------------------------------------------------
// Kernel A: per (b, chunk) — partial sum of x (for the mean) + chunk-local
// EWMA tails of x and x^2 with zero carry-in (chunk 0 uses true init).
// Scalar lanes (1 elem/thread) — measured fastest layout (R5 vs R4/R7).
// ---------------------------------------------------------------------------
__global__ __launch_bounds__(128) void kA(const float* __restrict__ x,
                                          float* __restrict__ Spart,
                                          float* __restrict__ l1e,
                                          float* __restrict__ l2e) {
    const int c = blockIdx.x;      // chunk
    const int b = blockIdx.y;      // batch
    const int d = threadIdx.x;     // feature

    const float* xp = x + ((size_t)b * T + (size_t)c * L) * D + d;

    float x0 = xp[0];
    float sum = x0;
    float l1, l2;
    if (c == 0) { l1 = x0;        l2 = x0 * x0; }
    else        { l1 = OMA * x0;  l2 = OMA * (x0 * x0); }

    for (int k = 1; k < L; ++k) {
        float xv = xp[(size_t)k * D];
        sum += xv;
        l1 = fmaf(ALPHA, l1, OMA * xv);
        l2 = fmaf(ALPHA, l2, OMA * (xv * xv));
    }

    const size_t o = ((size_t)b * NC + c) * D + d;
    Spart[o] = sum;
    l1e[o]   = l1;
    l2e[o]   = l2;
}

// ---------------------------------------------------------------------------
// Kernel B: per (b,d) — stitch chunk carries exactly:
//   E_end[c] = l_end[c] + alpha^L * E_end[c-1]
// Pass 2 rewrites the combined carry crw = carry2 - 2*mu*carry1 into carry1.
// NOTE: carry1 aliases Spart, carry2 aliases l1e (same-thread load-before-
// store at each index) — so NO __restrict__ here.
// ---------------------------------------------------------------------------
__global__ __launch_bounds__(256) void kB(const float* Spart,
                                          const float* l1e,
                                          const float* l2e,
                                          float* carry1,
                                          float* carry2,
                                          float* __restrict__ loc,
                                          float* __restrict__ scf) {
    const int tid = blockIdx.x * blockDim.x + threadIdx.x;   // b*D + d
    if (tid >= B * D) return;
    const int b = tid / D;
    const int d = tid % D;

    const float alphaL = (float)pow((double)ALPHA, (double)L);  // folded

    float sum = 0.0f, e1 = 0.0f, e2 = 0.0f;
    for (int c = 0; c < NC; ++c) {
        const size_t o = ((size_t)b * NC + c) * D + d;
        float sp = Spart[o];
        float t1 = l1e[o];
        float t2 = l2e[o];
        carry1[o] = e1;
        carry2[o] = e2;
        sum += sp;
        e1 = t1 + alphaL * e1;
        e2 = t2 + alphaL * e2;
    }

    const float mu = sum * (1.0f / (float)T);
    loc[tid] = mu;
    float ew = fmaxf(fmaf(mu, mu, fmaf(-2.0f * mu, e1, e2)), 0.0f);
    scf[tid] = fmaxf(sqrtf(0.5f * ew), 1e-5f);

    // fold carries: crw = carry2 - 2*mu*carry1 (stored into carry1)
    for (int c = 0; c < NC; ++c) {
        const size_t o = ((size_t)b * NC + c) * D + d;
        float c1 = carry1[o];
        float c2 = carry2[o];
        carry1[o] = fmaf(-2.0f * mu, c1, c2);
    }
}

// ---------------------------------------------------------------------------
// Kernel C: per (b, chunk) — single fused EWMA scan with the carry folded
// into the initial state:
//   s_k = alpha*s_{k-1} + (1-alpha)*x*(x-2mu),  s_0 = base_0 + alpha*crw
//   v = max(0.5*s + 0.5*mu^2, 1e-10) = scale^2 (eps clamp folded)
// Output stores are NON-TEMPORAL so the 138 MB of out doesn't evict x from
// the 256 MB LLC (keeps kC's x re-reads LLC-resident) — R5's win.
// ---------------------------------------------------------------------------
__global__ __launch_bounds__(128) void kC(const float* __restrict__ x,
                                          const float* __restrict__ crwb,
                                          const float* __restrict__ locg,
                                          float* __restrict__ out) {
    const int c = blockIdx.x;
    const int b = blockIdx.y;
    const int d = threadIdx.x;

    const size_t co = ((size_t)b * NC + c) * D + d;
    const float crw   = crwb[co];
    const float mu    = locg[b * D + d];
    const float twomu = 2.0f * mu;
    const float mu2h  = 0.5f * mu * mu;

    const float* xp = x   + ((size_t)b * T    + (size_t)c * L) * D + d;
    float*       op = out + ((size_t)b * TOUT + (size_t)c * L) * D + d;

    // k = 0
    float xv = xp[0];
    float g  = xv * (xv - twomu);
    float base = (c == 0) ? g : OMA * g;
    float s  = fmaf(ALPHA, crw, base);
    float vv = fmaxf(fmaf(0.5f, s, mu2h), 1e-10f);
    __builtin_nontemporal_store(t_to_z(xv - mu, vv), &op[0]);

    for (int k = 1; k < L; ++k) {
        xv = xp[(size_t)k * D];
        g  = xv * (xv - twomu);
        s  = fmaf(ALPHA, s, OMA * g);
        vv = fmaxf(fmaf(0.5f, s, mu2h), 1e-10f);
        __builtin_nontemporal_store(t_to_z(xv - mu, vv), &op[(size_t)k * D]);
    }
}

// ---------------------------------------------------------------------------
// Kernel D: forecasts — u = clip(ndtr(z)), student-t(4) ppf closed form.
// ---------------------------------------------------------------------------
__global__ __launch_bounds__(256) void kD(const float* __restrict__ zf,
                                          const float* __restrict__ loc,
                                          const float* __restrict__ scf,
                                          float* __restrict__ out) {
    const int idx = blockIdx.x * blockDim.x + threadIdx.x;
    if (idx >= B * P * D) return;
    const int d  = idx % D;
    const int bp = idx / D;
    const int p  = bp % P;
    const int b  = bp / P;

    float zv = zf[idx];
    float u = 0.5f * erfcf(-zv * INV_SQRT2);            // ndtr
    u = fminf(fmaxf(u, UCLIP), 1.0f - UCLIP);

    float a = 4.0f * u * (1.0f - u);
    a = fminf(fmaxf(a, UCLIP), 1.0f);
    float sa = sqrtf(a);
    float inner = cosf(acosf(sa) * (1.0f / 3.0f)) / sa - 1.0f;
    float qv = 2.0f * sqrtf(fmaxf(inner, 0.0f));

    float sgn = (u > 0.5f) ? 1.0f : ((u < 0.5f) ? -1.0f : 0.0f);
    float val = sgn * qv * scf[b * D + d] + loc[b * D + d];

    __builtin_nontemporal_store(val, &out[((size_t)b * TOUT + T + p) * D + d]);
}

// ---------------------------------------------------------------------------
extern "C" void kernel_launch(void* const* d_in, const int* in_sizes, int n_in,
                              void* d_out, int out_size, void* d_ws, size_t ws_size,
                              hipStream_t stream) {
    const float* x  = (const float*)d_in[0];   // (B,T,D)
    const float* zf = (const float*)d_in[1];   // (B,P,D)
    float* out = (float*)d_out;                // (B,T+P,D)

    float* ws = (float*)d_ws;
    const size_t NCH = (size_t)B * NC * D;     // 524288
    float* Spart  = ws;                        // reused as carry1 / crw
    float* l1e    = Spart + NCH;               // reused as carry2
    float* l2e    = l1e + NCH;
    float* loc    = l2e + NCH;                 // B*D
    float* scf    = loc + (size_t)B * D;       // B*D
    float* carry1 = Spart;                     // alias (see kB)
    float* carry2 = l1e;                       // alias (see kB)

    kA<<<dim3(NC, B), 128, 0, stream>>>(x, Spart, l1e, l2e);
    kB<<<(B * D + 255) / 256, 256, 0, stream>>>(Spart, l1e, l2e, carry1, carry2, loc, scf);
    kC<<<dim3(NC, B), 128, 0, stream>>>(x, carry1, loc, out);
    kD<<<(B * P * D + 255) / 256, 256, 0, stream>>>(zf, loc, scf, out);
}

// Round 9
// 83.327 us; speedup vs baseline: 1.2261x; 1.0153x over previous
//
#include <hip/hip_runtime.h>
#include <math.h>

// Problem constants (from reference setup_inputs)
namespace {
constexpr int B = 128;
constexpr int T = 2048;
constexpr int D = 128;
constexpr int P = 64;
constexpr int TOUT = T + P;          // 2112
constexpr int NC = 32;               // chunks along T (best measured: R2/R5)
constexpr int L = T / NC;            // 64 per chunk
constexpr float ALPHA = 0.94f;
constexpr float OMA = (float)(1.0 - 0.94);   // 1-alpha
constexpr float OMA_HALF = 0.03f;            // 0.5*(1-alpha)
constexpr float UCLIP = 1e-6f;
constexpr float INV_SQRT2 = 0.70710678118654752f;
}

// ---------------------------------------------------------------------------
// Direct composite map z = ndtri(student_t4_cdf(t)) = t * h(t^2), with
// h(q) expressed as a degree-4 polynomial in rc = 1/(8+q):
//   h = b0 + rc*(b1 + rc*(b2 + rc*(b3 + rc*b4)))
// Fit: Newton interpolation at 5 Chebyshev nodes in v1=8/(8+q) over
// q in [0, 33.34] (the provable range: ewma >= (1-alpha)(x-mu)^2 ==>
// t^2 <= 2/(1-alpha) - eps = 33.33; eps-clamp case gives the same bound).
// Cross-checked at 9 extra points: max |h err| ~1.1e-3 -> max z err ~6e-3,
// vs 0.765 absmax threshold. u-clip of the reference never triggers
// (|z| <= 2.86 < ndtri(1-1e-6) = 4.75), so no clamps are needed.
// ---------------------------------------------------------------------------
__device__ __forceinline__ float t_to_z_direct(float y, float vv) {
    float it = __builtin_amdgcn_rsqf(vv);     // 1/scale
    float t  = y * it;                        // student-t variate
    float q  = t * t;                         // in [0, 33.34]
    float rc = __builtin_amdgcn_rcpf(8.0f + q);
    float p;
    p = fmaf(-1453.744128f, rc, 610.201088f); // b4, b3  (8^k-scaled)
    p = fmaf(p, rc, -98.038976f);             // b2
    p = fmaf(p, rc, 10.835976f);              // b1
    p = fmaf(p, rc, 0.280213f);               // b0
    return t * p;
}

// ---------------------------------------------------------------------------
// Kernel A: per (b, chunk) — partial sum of x (for the mean) + chunk-local
// EWMA tails of x and x^2 with zero carry-in (chunk 0 uses true init).
// Scalar lanes (1 elem/thread) — measured fastest layout (R5 vs R4/R7).
// ---------------------------------------------------------------------------
__global__ __launch_bounds__(128) void kA(const float* __restrict__ x,
                                          float* __restrict__ Spart,
                                          float* __restrict__ l1e,
                                          float* __restrict__ l2e) {
    const int c = blockIdx.x;      // chunk
    const int b = blockIdx.y;      // batch
    const int d = threadIdx.x;     // feature

    const float* xp = x + ((size_t)b * T + (size_t)c * L) * D + d;

    float x0 = xp[0];
    float sum = x0;
    float l1, l2;
    if (c == 0) { l1 = x0;        l2 = x0 * x0; }
    else        { l1 = OMA * x0;  l2 = OMA * (x0 * x0); }

    for (int k = 1; k < L; ++k) {
        float xv = xp[(size_t)k * D];
        sum += xv;
        l1 = fmaf(ALPHA, l1, OMA * xv);
        l2 = fmaf(ALPHA, l2, OMA * (xv * xv));
    }

    const size_t o = ((size_t)b * NC + c) * D + d;
    Spart[o] = sum;
    l1e[o]   = l1;
    l2e[o]   = l2;
}

// ---------------------------------------------------------------------------
// Kernel B: per (b,d) — stitch chunk carries exactly:
//   E_end[c] = l_end[c] + alpha^L * E_end[c-1]
// Pass 2 rewrites the HALF combined carry crw_half = 0.5*(c2 - 2*mu*c1)
// into carry1 (kC scans the 0.5-scaled variable directly).
// NOTE: carry1 aliases Spart, carry2 aliases l1e (same-thread load-before-
// store at each index) — so NO __restrict__ here.
// ---------------------------------------------------------------------------
__global__ __launch_bounds__(256) void kB(const float* Spart,
                                          const float* l1e,
                                          const float* l2e,
                                          float* carry1,
                                          float* carry2,
                                          float* __restrict__ loc,
                                          float* __restrict__ scf) {
    const int tid = blockIdx.x * blockDim.x + threadIdx.x;   // b*D + d
    if (tid >= B * D) return;
    const int b = tid / D;
    const int d = tid % D;

    const float alphaL = (float)pow((double)ALPHA, (double)L);  // folded

    float sum = 0.0f, e1 = 0.0f, e2 = 0.0f;
    for (int c = 0; c < NC; ++c) {
        const size_t o = ((size_t)b * NC + c) * D + d;
        float sp = Spart[o];
        float t1 = l1e[o];
        float t2 = l2e[o];
        carry1[o] = e1;
        carry2[o] = e2;
        sum += sp;
        e1 = t1 + alphaL * e1;
        e2 = t2 + alphaL * e2;
    }

    const float mu = sum * (1.0f / (float)T);
    loc[tid] = mu;
    float ew = fmaxf(fmaf(mu, mu, fmaf(-2.0f * mu, e1, e2)), 0.0f);
    scf[tid] = fmaxf(sqrtf(0.5f * ew), 1e-5f);

    // fold carries: crw_half = 0.5*c2 - mu*c1 (stored into carry1)
    for (int c = 0; c < NC; ++c) {
        const size_t o = ((size_t)b * NC + c) * D + d;
        float c1 = carry1[o];
        float c2 = carry2[o];
        carry1[o] = fmaf(-mu, c1, 0.5f * c2);
    }
}

// ---------------------------------------------------------------------------
// Kernel C: per (b, chunk) — single fused EWMA scan of the 0.5-scaled
// variable sigma (= 0.5 * ewma-without-mu^2 term):
//   sigma_k = alpha*sigma_{k-1} + 0.5(1-alpha)*x*(x-2mu)
//   sigma_0 = 0.5*base_0 + alpha*crw_half
//   vv = max(sigma + 0.5*mu^2, 1e-10) = scale^2 (eps clamp folded)
// then z = t*h(t^2) directly (no erfinv, no clamps — see t_to_z_direct).
// NT stores keep x LLC-resident (R5's win).
// ---------------------------------------------------------------------------
__global__ __launch_bounds__(128) void kC(const float* __restrict__ x,
                                          const float* __restrict__ crwb,
                                          const float* __restrict__ locg,
                                          float* __restrict__ out) {
    const int c = blockIdx.x;
    const int b = blockIdx.y;
    const int d = threadIdx.x;

    const size_t co = ((size_t)b * NC + c) * D + d;
    const float crw   = crwb[co];              // 0.5-scaled carry
    const float mu    = locg[b * D + d];
    const float twomu = 2.0f * mu;
    const float mu2h  = 0.5f * mu * mu;

    const float* xp = x   + ((size_t)b * T    + (size_t)c * L) * D + d;
    float*       op = out + ((size_t)b * TOUT + (size_t)c * L) * D + d;

    // k = 0
    float xv = xp[0];
    float g  = xv * (xv - twomu);
    float base = (c == 0) ? 0.5f * g : OMA_HALF * g;
    float s  = fmaf(ALPHA, crw, base);
    float vv = fmaxf(s + mu2h, 1e-10f);
    __builtin_nontemporal_store(t_to_z_direct(xv - mu, vv), &op[0]);

    for (int k = 1; k < L; ++k) {
        xv = xp[(size_t)k * D];
        g  = xv * (xv - twomu);
        s  = fmaf(ALPHA, s, OMA_HALF * g);
        vv = fmaxf(s + mu2h, 1e-10f);
        __builtin_nontemporal_store(t_to_z_direct(xv - mu, vv), &op[(size_t)k * D]);
    }
}

// ---------------------------------------------------------------------------
// Kernel D: forecasts — u = clip(ndtr(z)), student-t(4) ppf closed form.
// ---------------------------------------------------------------------------
__global__ __launch_bounds__(256) void kD(const float* __restrict__ zf,
                                          const float* __restrict__ loc,
                                          const float* __restrict__ scf,
                                          float* __restrict__ out) {
    const int idx = blockIdx.x * blockDim.x + threadIdx.x;
    if (idx >= B * P * D) return;
    const int d  = idx % D;
    const int bp = idx / D;
    const int p  = bp % P;
    const int b  = bp / P;

    float zv = zf[idx];
    float u = 0.5f * erfcf(-zv * INV_SQRT2);            // ndtr
    u = fminf(fmaxf(u, UCLIP), 1.0f - UCLIP);

    float a = 4.0f * u * (1.0f - u);
    a = fminf(fmaxf(a, UCLIP), 1.0f);
    float sa = sqrtf(a);
    float inner = cosf(acosf(sa) * (1.0f / 3.0f)) / sa - 1.0f;
    float qv = 2.0f * sqrtf(fmaxf(inner, 0.0f));

    float sgn = (u > 0.5f) ? 1.0f : ((u < 0.5f) ? -1.0f : 0.0f);
    float val = sgn * qv * scf[b * D + d] + loc[b * D + d];

    __builtin_nontemporal_store(val, &out[((size_t)b * TOUT + T + p) * D + d]);
}

// ---------------------------------------------------------------------------
extern "C" void kernel_launch(void* const* d_in, const int* in_sizes, int n_in,
                              void* d_out, int out_size, void* d_ws, size_t ws_size,
                              hipStream_t stream) {
    const float* x  = (const float*)d_in[0];   // (B,T,D)
    const float* zf = (const float*)d_in[1];   // (B,P,D)
    float* out = (float*)d_out;                // (B,T+P,D)

    float* ws = (float*)d_ws;
    const size_t NCH = (size_t)B * NC * D;     // 524288
    float* Spart  = ws;                        // reused as carry1 / crw_half
    float* l1e    = Spart + NCH;               // reused as carry2
    float* l2e    = l1e + NCH;
    float* loc    = l2e + NCH;                 // B*D
    float* scf    = loc + (size_t)B * D;       // B*D
    float* carry1 = Spart;                     // alias (see kB)
    float* carry2 = l1e;                       // alias (see kB)

    kA<<<dim3(NC, B), 128, 0, stream>>>(x, Spart, l1e, l2e);
    kB<<<(B * D + 255) / 256, 256, 0, stream>>>(Spart, l1e, l2e, carry1, carry2, loc, scf);
    kC<<<dim3(NC, B), 128, 0, stream>>>(x, carry1, loc, out);
    kD<<<(B * P * D + 255) / 256, 256, 0, stream>>>(zf, loc, scf, out);
}